// Round 1
// baseline (1050.248 us; speedup 1.0000x reference)
//
#include <hip/hip_runtime.h>
#include <stdint.h>
#include <stddef.h>

typedef unsigned short u16;
typedef unsigned int u32;
typedef unsigned long long u64;
typedef __attribute__((ext_vector_type(4))) float f32x4;
typedef __attribute__((ext_vector_type(8))) __bf16 bf16x8;
typedef __attribute__((ext_vector_type(4))) short short4v;

#define NPOS 8192      // B*H*W
#define MROW 16384     // M
#define CDIM 1024      // C
#define ROWLEN 2048    // packed row: per 8-k chunk: 8 hi bf16 then 8 lo bf16 -> 2048 u16 per row

__device__ __forceinline__ u16 f2bf(float x){
  union { float f; u32 u; } z; z.f = x;
  u32 u = z.u;
  return (u16)((u + 0x7fffu + ((u >> 16) & 1u)) >> 16);   // RNE
}
__device__ __forceinline__ float bf2f(u16 h){
  union { u32 u; float f; } z; z.u = ((u32)h) << 16; return z.f;
}
__device__ __forceinline__ u32 fkey(float f){   // order-preserving float->uint
  union { float f; u32 u; } z; z.f = f;
  u32 b = z.u;
  return b ^ ((b & 0x80000000u) ? 0xffffffffu : 0x80000000u);
}

__device__ __forceinline__ float block_sum256(float v, float* sb){
  #pragma unroll
  for(int o = 32; o; o >>= 1) v += __shfl_xor(v, o, 64);
  __syncthreads();                    // protect sb across repeated calls
  int lane = threadIdx.x & 63, w = threadIdx.x >> 6;
  if(lane == 0) sb[w] = v;
  __syncthreads();
  return sb[0] + sb[1] + sb[2] + sb[3];   // same fixed order on all threads
}

// ---- K1: split memory bank into bf16 hi/lo pack + row sum of squares; init minmax ----
__global__ __launch_bounds__(256) void k_prep_mb(const float* __restrict__ mb, u16* __restrict__ mpack,
                                                 float* __restrict__ m_sq, u32* __restrict__ minmax){
  __shared__ float sb[4];
  int row = blockIdx.x, t = threadIdx.x;
  if(row == 0 && t == 0){ minmax[0] = 0x7f800000u; minmax[1] = 0u; }
  const float4 v = ((const float4*)(mb + (size_t)row * CDIM))[t];   // k = 4t..4t+3
  int kc = t >> 1, j0 = (t & 1) * 4;
  u16* base = mpack + (size_t)row * ROWLEN + kc * 16 + j0;
  float xs[4] = {v.x, v.y, v.z, v.w};
  short4v hi, lo;
  #pragma unroll
  for(int j = 0; j < 4; j++){
    u16 h = f2bf(xs[j]);
    u16 l = f2bf(xs[j] - bf2f(h));
    hi[j] = (short)h; lo[j] = (short)l;
  }
  *(short4v*)base = hi;
  *(short4v*)(base + 8) = lo;
  float s = v.x*v.x + v.y*v.y + v.z*v.z + v.w*v.w;
  #pragma unroll
  for(int o = 32; o; o >>= 1) s += __shfl_xor(s, o, 64);
  int lane = t & 63, w = t >> 6;
  if(lane == 0) sb[w] = s;
  __syncthreads();
  if(t == 0) m_sq[row] = sb[0] + sb[1] + sb[2] + sb[3];
}

// ---- K2: gather features (B,C,HW) -> packed (N,C) bf16 hi/lo via LDS transpose ----
__global__ __launch_bounds__(256) void k_prep_f(const float* __restrict__ feat, u16* __restrict__ fpack){
  __shared__ float tile[64][65];
  int b = blockIdx.z, c0 = blockIdx.y * 64, hw0 = blockIdx.x * 64;
  int t = threadIdx.x, a = t & 63, g = t >> 6;
  const float* fb = feat + ((size_t)b * CDIM + c0) * 1024 + hw0;
  #pragma unroll 4
  for(int r = 0; r < 16; r++){
    int cL = r * 4 + g;
    tile[cL][a] = fb[(size_t)cL * 1024 + a];      // coalesced over hw
  }
  __syncthreads();
  #pragma unroll 4
  for(int r = 0; r < 16; r++){
    int hwL = r * 4 + g;
    int n = b * 1024 + hw0 + hwL;
    int c = c0 + a;
    float x = tile[a][hwL];
    u16 h = f2bf(x);
    u16 l = f2bf(x - bf2f(h));
    u16* base = fpack + (size_t)n * ROWLEN + (c >> 3) * 16 + (c & 7);
    base[0] = h; base[8] = l;
  }
}

// ---- K3: f_sq from packed (hi+lo) row ----
__global__ __launch_bounds__(256) void k_fsq(const u16* __restrict__ fpack, float* __restrict__ f_sq){
  __shared__ float sb[4];
  int n = blockIdx.x, t = threadIdx.x;
  const u16* fp = fpack + (size_t)n * ROWLEN + (t >> 1) * 16 + (t & 1) * 4;
  float s = 0.f;
  #pragma unroll
  for(int j = 0; j < 4; j++){
    float x = bf2f(fp[j]) + bf2f(fp[j + 8]);
    s += x * x;
  }
  #pragma unroll
  for(int o = 32; o; o >>= 1) s += __shfl_xor(s, o, 64);
  int lane = t & 63, w = t >> 6;
  if(lane == 0) sb[w] = s;
  __syncthreads();
  if(t == 0) f_sq[n] = sb[0] + sb[1] + sb[2] + sb[3];
}

__device__ __forceinline__ f32x4 mfma16(bf16x8 a, bf16x8 b, f32x4 c){
  return __builtin_amdgcn_mfma_f32_16x16x32_bf16(a, b, c, 0, 0, 0);
}

// ---- K4: split-bf16 GEMM (cross = f.mb^T via ah*bh + ah*bl + al*bh) with per-(row, col-tile)
//          argmin epilogue: cand[row][ct] = pack(m_sq[col] - 2*cross, col) ----
__global__ __launch_bounds__(256) void k_gemm(const u16* __restrict__ fpack, const u16* __restrict__ mpack,
                                              const float* __restrict__ m_sq, u64* __restrict__ cand){
  __shared__ u16 Ah[128][40];   // +8 u16 pad -> 80B stride, conflict-light ds_read_b128
  __shared__ u16 Al[128][40];
  __shared__ u16 Bh[128][40];
  __shared__ u16 Bl[128][40];
  int rt = blockIdx.y, ct = blockIdx.x;
  int t = threadIdx.x, lane = t & 63, wid = t >> 6;
  int wm = wid >> 1, wn = wid & 1;
  const f32x4 zero = {0.f, 0.f, 0.f, 0.f};
  f32x4 acc[4][4];
  #pragma unroll
  for(int i = 0; i < 4; i++)
    #pragma unroll
    for(int j = 0; j < 4; j++) acc[i][j] = zero;

  int srow = t >> 1, shalf = t & 1;
  const u16* ap = fpack + (size_t)(rt * 128 + srow) * ROWLEN + shalf * 32;
  const u16* bp = mpack + (size_t)(ct * 128 + srow) * ROWLEN + shalf * 32;
  int fr = lane & 15, fk = (lane >> 4) * 8;

  for(int kt = 0; kt < 32; ++kt){
    const u16* a4 = ap + kt * 64;
    const u16* b4 = bp + kt * 64;
    bf16x8 a0 = *(const bf16x8*)(a4);        // hi chunk0
    bf16x8 a1 = *(const bf16x8*)(a4 + 8);    // lo chunk0
    bf16x8 a2 = *(const bf16x8*)(a4 + 16);   // hi chunk1
    bf16x8 a3 = *(const bf16x8*)(a4 + 24);   // lo chunk1
    bf16x8 b0 = *(const bf16x8*)(b4);
    bf16x8 b1 = *(const bf16x8*)(b4 + 8);
    bf16x8 b2 = *(const bf16x8*)(b4 + 16);
    bf16x8 b3 = *(const bf16x8*)(b4 + 24);
    *(bf16x8*)&Ah[srow][shalf * 16 + 0] = a0;
    *(bf16x8*)&Al[srow][shalf * 16 + 0] = a1;
    *(bf16x8*)&Ah[srow][shalf * 16 + 8] = a2;
    *(bf16x8*)&Al[srow][shalf * 16 + 8] = a3;
    *(bf16x8*)&Bh[srow][shalf * 16 + 0] = b0;
    *(bf16x8*)&Bl[srow][shalf * 16 + 0] = b1;
    *(bf16x8*)&Bh[srow][shalf * 16 + 8] = b2;
    *(bf16x8*)&Bl[srow][shalf * 16 + 8] = b3;
    __syncthreads();

    bf16x8 fah[4], fal[4], fbh[4], fbl[4];
    #pragma unroll
    for(int mi = 0; mi < 4; mi++){
      int r = wm * 64 + mi * 16 + fr;
      fah[mi] = *(const bf16x8*)&Ah[r][fk];
      fal[mi] = *(const bf16x8*)&Al[r][fk];
    }
    #pragma unroll
    for(int ni = 0; ni < 4; ni++){
      int r = wn * 64 + ni * 16 + fr;
      fbh[ni] = *(const bf16x8*)&Bh[r][fk];
      fbl[ni] = *(const bf16x8*)&Bl[r][fk];
    }
    #pragma unroll
    for(int mi = 0; mi < 4; mi++)
      #pragma unroll
      for(int ni = 0; ni < 4; ni++){
        acc[mi][ni] = mfma16(fah[mi], fbh[ni], acc[mi][ni]);
        acc[mi][ni] = mfma16(fah[mi], fbl[ni], acc[mi][ni]);
        acc[mi][ni] = mfma16(fal[mi], fbh[ni], acc[mi][ni]);
      }
    __syncthreads();
  }

  // epilogue: per-row argmin of (m_sq[col] - 2*cross) over this block's 128 cols
  float msq[4];
  #pragma unroll
  for(int ni = 0; ni < 4; ni++) msq[ni] = m_sq[ct * 128 + wn * 64 + ni * 16 + fr];
  u64* rl = (u64*)&Ah[0][0];   // reuse LDS (all waves past final barrier)
  #pragma unroll
  for(int mi = 0; mi < 4; mi++){
    #pragma unroll
    for(int j = 0; j < 4; j++){
      float best = msq[0] - 2.f * acc[mi][0][j];
      int bni = 0;
      #pragma unroll
      for(int ni = 1; ni < 4; ni++){
        float u = msq[ni] - 2.f * acc[mi][ni][j];
        if(u < best){ best = u; bni = ni; }
      }
      u32 col = (u32)(ct * 128 + wn * 64 + bni * 16 + fr);
      u64 key = ((u64)fkey(best) << 32) | col;
      #pragma unroll
      for(int m = 1; m < 16; m <<= 1){   // butterfly over the 16 cols held by this lane group
        u64 o = __shfl_xor(key, m, 64);
        key = o < key ? o : key;
      }
      if(fr == 0){
        int row_local = mi * 16 + ((lane >> 4) << 2) + j;
        rl[wm * 128 + wn * 64 + row_local] = key;
      }
    }
  }
  __syncthreads();
  if(t < 128){
    int wmx = t >> 6, r = t & 63;
    u64 x = rl[wmx * 128 + r], y = rl[wmx * 128 + 64 + r];
    cand[(size_t)(rt * 128 + wmx * 64 + r) * 128 + ct] = x < y ? x : y;
  }
}

// ---- K5: per row: top-2 candidates across tiles, exact fp32 re-check, influence ----
__global__ __launch_bounds__(256) void k_finalize(const u64* __restrict__ cand, const u16* __restrict__ fpack,
    const float* __restrict__ mb, const float* __restrict__ m_sq, const float* __restrict__ f_sq,
    float* __restrict__ inf_arr, u32* __restrict__ minmax){
  __shared__ u64 cl[128];
  __shared__ float sb[4];
  __shared__ int cbest[2];
  int n = blockIdx.x, t = threadIdx.x;
  if(t < 128) cl[t] = cand[(size_t)n * 128 + t];
  __syncthreads();
  if(t == 0){
    u64 b1 = (u64)-1, b2 = (u64)-1;
    for(int i = 0; i < 128; i++){
      u64 x = cl[i];
      if(x < b1){ b2 = b1; b1 = x; } else if(x < b2){ b2 = x; }
    }
    cbest[0] = (int)(b1 & 0xffffffffull);
    cbest[1] = (int)(b2 & 0xffffffffull);
  }
  __syncthreads();
  int c1 = cbest[0], c2 = cbest[1];
  float fv[4];
  const u16* fp = fpack + (size_t)n * ROWLEN + (t >> 1) * 16 + (t & 1) * 4;
  #pragma unroll
  for(int j = 0; j < 4; j++) fv[j] = bf2f(fp[j]) + bf2f(fp[j + 8]);   // ~f to 2^-17
  const float4 m1 = ((const float4*)(mb + (size_t)c1 * CDIM))[t];
  const float4 m2 = ((const float4*)(mb + (size_t)c2 * CDIM))[t];
  float p1 = fv[0]*m1.x + fv[1]*m1.y + fv[2]*m1.z + fv[3]*m1.w;
  float p2 = fv[0]*m2.x + fv[1]*m2.y + fv[2]*m2.z + fv[3]*m2.w;
  float s1 = block_sum256(p1, sb);
  float s2 = block_sum256(p2, sb);
  float fs = f_sq[n];
  float d1 = sqrtf(fmaxf(fs + m_sq[c1] - 2.f * s1, 0.f) + 1e-8f);
  float d2 = sqrtf(fmaxf(fs + m_sq[c2] - 2.f * s2, 0.f) + 1e-8f);
  bool pick1 = (d1 < d2) || (d1 == d2 && c1 < c2);
  float d0 = (pick1 ? d1 : d2) + 1e-8f;
  float4 mv = pick1 ? m1 : m2;
  float pa = fabsf(fv[0]-mv.x) + fabsf(fv[1]-mv.y) + fabsf(fv[2]-mv.z) + fabsf(fv[3]-mv.w);
  float sab = block_sum256(pa, sb);
  if(t == 0){
    float inf = sab / (1024.0f * d0);
    inf_arr[n] = inf;
    atomicMin(&minmax[0], __float_as_uint(inf));   // inf >= 0 -> bit order == float order
    atomicMax(&minmax[1], __float_as_uint(inf));
  }
}

// ---- K6: influence_norm + noise_std maps ----
__global__ void k_maps(const float* __restrict__ inf_arr, const u32* __restrict__ minmax,
                       float* __restrict__ out, float* __restrict__ nstd_arr){
  int n = blockIdx.x * 256 + threadIdx.x;
  float imin = __uint_as_float(minmax[0]);
  float imax = __uint_as_float(minmax[1]);
  float denom = imax - imin;
  float x = inf_arr[n];
  float norm = (denom > 1e-8f) ? ((x - imin) / fmaxf(denom, 1e-8f)) : 0.0f;
  float nsv = 0.01f + norm * 0.49f;
  out[8388608 + n] = norm;       // influence_map
  out[8396800 + n] = nsv;        // noise_std_map
  nstd_arr[n] = nsv;
}

// ---- K7: noised = features + noise * std  (LDS transpose keeps both sides coalesced) ----
__global__ __launch_bounds__(256) void k_noise(const float* __restrict__ feat, const float* __restrict__ noise,
                                               const float* __restrict__ nstd_arr, float* __restrict__ out){
  __shared__ float tile[64][65];
  __shared__ float ns[64];
  int b = blockIdx.z, c0 = blockIdx.y * 64, hw0 = blockIdx.x * 64;
  int t = threadIdx.x, a = t & 63, g = t >> 6;
  if(t < 64) ns[t] = nstd_arr[b * 1024 + hw0 + t];
  #pragma unroll 4
  for(int r = 0; r < 16; r++){
    int j = r * 4 + g;   // hw row
    tile[a][j] = noise[((size_t)(b * 1024 + hw0 + j)) * CDIM + c0 + a];   // coalesced over c
  }
  __syncthreads();
  #pragma unroll 4
  for(int r = 0; r < 16; r++){
    int i = r * 4 + g;   // c offset
    size_t idx = ((size_t)b * CDIM + c0 + i) * 1024 + hw0 + a;
    out[idx] = feat[idx] + tile[i][a] * ns[a];                            // coalesced over hw
  }
}

extern "C" void kernel_launch(void* const* d_in, const int* in_sizes, int n_in,
                              void* d_out, int out_size, void* d_ws, size_t ws_size,
                              hipStream_t stream){
  const float* features = (const float*)d_in[0];
  const float* mb       = (const float*)d_in[1];
  const float* noise    = (const float*)d_in[2];
  float* out = (float*)d_out;
  char* ws = (char*)d_ws;

  // f-pack (32MB) lives in d_out's noised region (exactly 32MB); overwritten last by k_noise.
  u16* fpack = (u16*)d_out;

  size_t off = 0;
  u16* mpack     = (u16*)(ws + off);   off += (size_t)MROW * ROWLEN * 2;  // 64MB
  float* m_sq    = (float*)(ws + off); off += (size_t)MROW * 4;
  float* f_sq    = (float*)(ws + off); off += (size_t)NPOS * 4;
  float* inf_arr = (float*)(ws + off); off += (size_t)NPOS * 4;
  float* nstd_a  = (float*)(ws + off); off += (size_t)NPOS * 4;
  u32* minmax    = (u32*)(ws + off);   off += 256;
  u64* cand      = (u64*)(ws + off);   off += (size_t)NPOS * 128 * 8;     // 8MB

  k_prep_mb<<<MROW, 256, 0, stream>>>(mb, mpack, m_sq, minmax);
  k_prep_f<<<dim3(16, 16, 8), 256, 0, stream>>>(features, fpack);
  k_fsq<<<NPOS, 256, 0, stream>>>(fpack, f_sq);
  k_gemm<<<dim3(128, 64), 256, 0, stream>>>(fpack, mpack, m_sq, cand);
  k_finalize<<<NPOS, 256, 0, stream>>>(cand, fpack, mb, m_sq, f_sq, inf_arr, minmax);
  k_maps<<<32, 256, 0, stream>>>(inf_arr, minmax, out, nstd_a);
  k_noise<<<dim3(16, 16, 8), 256, 0, stream>>>(features, noise, nstd_a, out);
}

// Round 2
// 849.911 us; speedup vs baseline: 1.2357x; 1.2357x over previous
//
#include <hip/hip_runtime.h>
#include <stdint.h>
#include <stddef.h>

typedef unsigned short u16;
typedef unsigned int u32;
typedef unsigned long long u64;
typedef __attribute__((ext_vector_type(4))) float f32x4;
typedef __attribute__((ext_vector_type(8))) __bf16 bf16x8;
typedef __attribute__((ext_vector_type(4))) short short4v;

#define NPOS 8192      // B*H*W
#define MROW 16384     // M
#define CDIM 1024      // C
#define ROWLEN 2048    // packed row: per 8-k chunk: 8 hi bf16 then 8 lo bf16 -> 2048 u16 per row

__device__ __forceinline__ u16 f2bf(float x){
  union { float f; u32 u; } z; z.f = x;
  u32 u = z.u;
  return (u16)((u + 0x7fffu + ((u >> 16) & 1u)) >> 16);   // RNE
}
__device__ __forceinline__ float bf2f(u16 h){
  union { u32 u; float f; } z; z.u = ((u32)h) << 16; return z.f;
}
__device__ __forceinline__ u32 fkey(float f){   // order-preserving float->uint
  union { float f; u32 u; } z; z.f = f;
  u32 b = z.u;
  return b ^ ((b & 0x80000000u) ? 0xffffffffu : 0x80000000u);
}

__device__ __forceinline__ float block_sum256(float v, float* sb){
  #pragma unroll
  for(int o = 32; o; o >>= 1) v += __shfl_xor(v, o, 64);
  __syncthreads();                    // protect sb across repeated calls
  int lane = threadIdx.x & 63, w = threadIdx.x >> 6;
  if(lane == 0) sb[w] = v;
  __syncthreads();
  return sb[0] + sb[1] + sb[2] + sb[3];   // same fixed order on all threads
}

// async global->LDS, 16B per lane (wave-uniform LDS base + lane*16; global addr is per-lane)
__device__ __forceinline__ void gload16(const u16* g, u16* l){
  __builtin_amdgcn_global_load_lds((const __attribute__((address_space(1))) u32*)g,
                                   (__attribute__((address_space(3))) u32*)l, 16, 0, 0);
}

// ---- K1: split memory bank into bf16 hi/lo pack + row sum of squares; init minmax ----
__global__ __launch_bounds__(256) void k_prep_mb(const float* __restrict__ mb, u16* __restrict__ mpack,
                                                 float* __restrict__ m_sq, u32* __restrict__ minmax){
  __shared__ float sb[4];
  int row = blockIdx.x, t = threadIdx.x;
  if(row == 0 && t == 0){ minmax[0] = 0x7f800000u; minmax[1] = 0u; }
  const float4 v = ((const float4*)(mb + (size_t)row * CDIM))[t];   // k = 4t..4t+3
  int kc = t >> 1, j0 = (t & 1) * 4;
  u16* base = mpack + (size_t)row * ROWLEN + kc * 16 + j0;
  float xs[4] = {v.x, v.y, v.z, v.w};
  short4v hi, lo;
  #pragma unroll
  for(int j = 0; j < 4; j++){
    u16 h = f2bf(xs[j]);
    u16 l = f2bf(xs[j] - bf2f(h));
    hi[j] = (short)h; lo[j] = (short)l;
  }
  *(short4v*)base = hi;
  *(short4v*)(base + 8) = lo;
  float s = v.x*v.x + v.y*v.y + v.z*v.z + v.w*v.w;
  #pragma unroll
  for(int o = 32; o; o >>= 1) s += __shfl_xor(s, o, 64);
  int lane = t & 63, w = t >> 6;
  if(lane == 0) sb[w] = s;
  __syncthreads();
  if(t == 0) m_sq[row] = sb[0] + sb[1] + sb[2] + sb[3];
}

// ---- K2: gather features (B,C,HW) -> packed (N,C) bf16 hi/lo via LDS transpose ----
__global__ __launch_bounds__(256) void k_prep_f(const float* __restrict__ feat, u16* __restrict__ fpack){
  __shared__ float tile[64][65];
  int b = blockIdx.z, c0 = blockIdx.y * 64, hw0 = blockIdx.x * 64;
  int t = threadIdx.x, a = t & 63, g = t >> 6;
  const float* fb = feat + ((size_t)b * CDIM + c0) * 1024 + hw0;
  #pragma unroll 4
  for(int r = 0; r < 16; r++){
    int cL = r * 4 + g;
    tile[cL][a] = fb[(size_t)cL * 1024 + a];      // coalesced over hw
  }
  __syncthreads();
  #pragma unroll 4
  for(int r = 0; r < 16; r++){
    int hwL = r * 4 + g;
    int n = b * 1024 + hw0 + hwL;
    int c = c0 + a;
    float x = tile[a][hwL];
    u16 h = f2bf(x);
    u16 l = f2bf(x - bf2f(h));
    u16* base = fpack + (size_t)n * ROWLEN + (c >> 3) * 16 + (c & 7);
    base[0] = h; base[8] = l;
  }
}

__device__ __forceinline__ f32x4 mfma16(bf16x8 a, bf16x8 b, f32x4 c){
  return __builtin_amdgcn_mfma_f32_16x16x32_bf16(a, b, c, 0, 0, 0);
}

// ---- K4: split-bf16 GEMM, 256x256 tile, 8 waves (2x4), per-wave 128x64, BK=32,
//          gload_lds(16B) staging with inverse-XOR-swizzled source, double-buffered LDS,
//          one __syncthreads per K-tile. Epilogue: per-(row, 256-col-tile) argmin key. ----
__global__ __launch_bounds__(512, 2) void k_gemm(const u16* __restrict__ fpack, const u16* __restrict__ mpack,
                                                 const float* __restrict__ m_sq, u64* __restrict__ cand){
  // [buf][A=0/B=1][row 0..255][64 u16 = 128B = 8 blocks of 16B], block b stored at slot b^(row&7)
  __shared__ u16 lds[2][2][256][64];   // 128 KB
  int rt = blockIdx.y, ct = blockIdx.x;
  int t = threadIdx.x, lane = t & 63, wid = t >> 6;
  int wm = wid >> 2, wn = wid & 3;        // wave tile: rows wm*128, cols wn*64
  int fr = lane & 15, g = lane >> 4;      // fragment row sel / k-group sel
  const u16* Ag = fpack + (size_t)(rt * 256) * ROWLEN;
  const u16* Bg = mpack + (size_t)(ct * 256) * ROWLEN;
  int srow = t >> 3, slot = t & 7;        // staging: 8 threads per row, 64 rows per round

  const f32x4 zero = {0.f, 0.f, 0.f, 0.f};
  f32x4 acc[8][4];
  #pragma unroll
  for(int i = 0; i < 8; i++)
    #pragma unroll
    for(int j = 0; j < 4; j++) acc[i][j] = zero;

  auto STAGE = [&](int buf, int kt){
    #pragma unroll
    for(int r = 0; r < 4; r++){
      int row = r * 64 + srow;
      int sblk = slot ^ (row & 7);                     // inverse swizzle on SOURCE
      gload16(Ag + (size_t)row * ROWLEN + kt * 64 + sblk * 8, &lds[buf][0][row][slot * 8]);
    }
    #pragma unroll
    for(int r = 0; r < 4; r++){
      int row = r * 64 + srow;
      int sblk = slot ^ (row & 7);
      gload16(Bg + (size_t)row * ROWLEN + kt * 64 + sblk * 8, &lds[buf][1][row][slot * 8]);
    }
  };

  STAGE(0, 0);
  __syncthreads();        // drains vmcnt; buf0 ready
  int cur = 0;
  for(int kt = 0; kt < 32; ++kt){
    if(kt < 31) STAGE(cur ^ 1, kt + 1);   // issue next-tile loads BEFORE compute
    bf16x8 fbh[4], fbl[4];
    #pragma unroll
    for(int ni = 0; ni < 4; ni++){
      int r = wn * 64 + ni * 16 + fr;
      const u16* base = &lds[cur][1][r][0];
      fbh[ni] = *(const bf16x8*)(base + (((2 * g + 0) ^ (r & 7)) << 3));
      fbl[ni] = *(const bf16x8*)(base + (((2 * g + 1) ^ (r & 7)) << 3));
    }
    #pragma unroll
    for(int mi = 0; mi < 8; mi++){
      int r = wm * 128 + mi * 16 + fr;
      const u16* base = &lds[cur][0][r][0];
      bf16x8 ah = *(const bf16x8*)(base + (((2 * g + 0) ^ (r & 7)) << 3));
      bf16x8 al = *(const bf16x8*)(base + (((2 * g + 1) ^ (r & 7)) << 3));
      #pragma unroll
      for(int ni = 0; ni < 4; ni++){
        acc[mi][ni] = mfma16(ah, fbh[ni], acc[mi][ni]);   // same product order as before:
        acc[mi][ni] = mfma16(ah, fbl[ni], acc[mi][ni]);   // hh, h*l, l*h -> bitwise-identical acc
        acc[mi][ni] = mfma16(al, fbh[ni], acc[mi][ni]);
      }
    }
    __syncthreads();      // drains vmcnt (next buf staged) + all lds reads done
    cur ^= 1;
  }

  // epilogue: per-row argmin of (m_sq[col] - 2*cross) over this block's 256 cols
  float msq[4];
  #pragma unroll
  for(int ni = 0; ni < 4; ni++) msq[ni] = m_sq[ct * 256 + wn * 64 + ni * 16 + fr];
  u64* rl = (u64*)&lds[0][0][0][0];   // 4*256 u64 = 8KB scratch (all waves past final barrier)
  #pragma unroll
  for(int mi = 0; mi < 8; mi++){
    #pragma unroll
    for(int j = 0; j < 4; j++){
      float best = msq[0] - 2.f * acc[mi][0][j];
      int bni = 0;
      #pragma unroll
      for(int ni = 1; ni < 4; ni++){
        float u = msq[ni] - 2.f * acc[mi][ni][j];
        if(u < best){ best = u; bni = ni; }
      }
      u32 col = (u32)(ct * 256 + wn * 64 + bni * 16 + fr);
      u64 key = ((u64)fkey(best) << 32) | col;
      #pragma unroll
      for(int m = 1; m < 16; m <<= 1){   // butterfly over the 16 fr-lanes of this k-group
        u64 o = __shfl_xor(key, m, 64);
        key = o < key ? o : key;
      }
      if(fr == 0){
        int row_local = wm * 128 + mi * 16 + g * 4 + j;
        rl[wn * 256 + row_local] = key;
      }
    }
  }
  __syncthreads();
  if(t < 256){
    u64 x0 = rl[t], x1 = rl[256 + t], x2 = rl[512 + t], x3 = rl[768 + t];
    u64 m0 = x0 < x1 ? x0 : x1;
    u64 m1 = x2 < x3 ? x2 : x3;
    cand[(size_t)(rt * 256 + t) * 64 + ct] = m0 < m1 ? m0 : m1;
  }
}

// ---- K5: per row: top-2 candidates across 64 tiles, exact fp32 re-check, influence ----
__global__ __launch_bounds__(256) void k_finalize(const u64* __restrict__ cand, const u16* __restrict__ fpack,
    const float* __restrict__ mb, const float* __restrict__ m_sq,
    float* __restrict__ inf_arr, u32* __restrict__ minmax){
  __shared__ u64 cl[64];
  __shared__ float sb[4];
  __shared__ int cbest[2];
  int n = blockIdx.x, t = threadIdx.x;
  if(t < 64) cl[t] = cand[(size_t)n * 64 + t];
  __syncthreads();
  if(t == 0){
    u64 b1 = (u64)-1, b2 = (u64)-1;
    for(int i = 0; i < 64; i++){
      u64 x = cl[i];
      if(x < b1){ b2 = b1; b1 = x; } else if(x < b2){ b2 = x; }
    }
    cbest[0] = (int)(b1 & 0xffffffffull);
    cbest[1] = (int)(b2 & 0xffffffffull);
  }
  __syncthreads();
  int c1 = cbest[0], c2 = cbest[1];
  float fv[4];
  const u16* fp = fpack + (size_t)n * ROWLEN + (t >> 1) * 16 + (t & 1) * 4;
  #pragma unroll
  for(int j = 0; j < 4; j++) fv[j] = bf2f(fp[j]) + bf2f(fp[j + 8]);   // ~f to 2^-17
  // f_sq computed here (same reduction structure as the old k_fsq)
  float sq = fv[0]*fv[0] + fv[1]*fv[1] + fv[2]*fv[2] + fv[3]*fv[3];
  float fs = block_sum256(sq, sb);
  const float4 m1 = ((const float4*)(mb + (size_t)c1 * CDIM))[t];
  const float4 m2 = ((const float4*)(mb + (size_t)c2 * CDIM))[t];
  float p1 = fv[0]*m1.x + fv[1]*m1.y + fv[2]*m1.z + fv[3]*m1.w;
  float p2 = fv[0]*m2.x + fv[1]*m2.y + fv[2]*m2.z + fv[3]*m2.w;
  float s1 = block_sum256(p1, sb);
  float s2 = block_sum256(p2, sb);
  float d1 = sqrtf(fmaxf(fs + m_sq[c1] - 2.f * s1, 0.f) + 1e-8f);
  float d2 = sqrtf(fmaxf(fs + m_sq[c2] - 2.f * s2, 0.f) + 1e-8f);
  bool pick1 = (d1 < d2) || (d1 == d2 && c1 < c2);
  float d0 = (pick1 ? d1 : d2) + 1e-8f;
  float4 mv = pick1 ? m1 : m2;
  float pa = fabsf(fv[0]-mv.x) + fabsf(fv[1]-mv.y) + fabsf(fv[2]-mv.z) + fabsf(fv[3]-mv.w);
  float sab = block_sum256(pa, sb);
  if(t == 0){
    float inf = sab / (1024.0f * d0);
    inf_arr[n] = inf;
    atomicMin(&minmax[0], __float_as_uint(inf));   // inf >= 0 -> bit order == float order
    atomicMax(&minmax[1], __float_as_uint(inf));
  }
}

// ---- K6: influence_norm + noise_std maps ----
__global__ void k_maps(const float* __restrict__ inf_arr, const u32* __restrict__ minmax,
                       float* __restrict__ out, float* __restrict__ nstd_arr){
  int n = blockIdx.x * 256 + threadIdx.x;
  float imin = __uint_as_float(minmax[0]);
  float imax = __uint_as_float(minmax[1]);
  float denom = imax - imin;
  float x = inf_arr[n];
  float norm = (denom > 1e-8f) ? ((x - imin) / fmaxf(denom, 1e-8f)) : 0.0f;
  float nsv = 0.01f + norm * 0.49f;
  out[8388608 + n] = norm;       // influence_map
  out[8396800 + n] = nsv;        // noise_std_map
  nstd_arr[n] = nsv;
}

// ---- K7: noised = features + noise * std  (LDS transpose keeps both sides coalesced) ----
__global__ __launch_bounds__(256) void k_noise(const float* __restrict__ feat, const float* __restrict__ noise,
                                               const float* __restrict__ nstd_arr, float* __restrict__ out){
  __shared__ float tile[64][65];
  __shared__ float ns[64];
  int b = blockIdx.z, c0 = blockIdx.y * 64, hw0 = blockIdx.x * 64;
  int t = threadIdx.x, a = t & 63, g = t >> 6;
  if(t < 64) ns[t] = nstd_arr[b * 1024 + hw0 + t];
  #pragma unroll 4
  for(int r = 0; r < 16; r++){
    int j = r * 4 + g;   // hw row
    tile[a][j] = noise[((size_t)(b * 1024 + hw0 + j)) * CDIM + c0 + a];   // coalesced over c
  }
  __syncthreads();
  #pragma unroll 4
  for(int r = 0; r < 16; r++){
    int i = r * 4 + g;   // c offset
    size_t idx = ((size_t)b * CDIM + c0 + i) * 1024 + hw0 + a;
    out[idx] = feat[idx] + tile[i][a] * ns[a];                            // coalesced over hw
  }
}

extern "C" void kernel_launch(void* const* d_in, const int* in_sizes, int n_in,
                              void* d_out, int out_size, void* d_ws, size_t ws_size,
                              hipStream_t stream){
  const float* features = (const float*)d_in[0];
  const float* mb       = (const float*)d_in[1];
  const float* noise    = (const float*)d_in[2];
  float* out = (float*)d_out;
  char* ws = (char*)d_ws;

  // f-pack (32MB) lives in d_out's noised region (exactly 32MB); overwritten last by k_noise.
  u16* fpack = (u16*)d_out;

  size_t off = 0;
  u16* mpack     = (u16*)(ws + off);   off += (size_t)MROW * ROWLEN * 2;  // 64MB
  float* m_sq    = (float*)(ws + off); off += (size_t)MROW * 4;
  float* inf_arr = (float*)(ws + off); off += (size_t)NPOS * 4;
  float* nstd_a  = (float*)(ws + off); off += (size_t)NPOS * 4;
  u32* minmax    = (u32*)(ws + off);   off += 256;
  u64* cand      = (u64*)(ws + off);   off += (size_t)NPOS * 64 * 8;      // 4MB

  k_prep_mb<<<MROW, 256, 0, stream>>>(mb, mpack, m_sq, minmax);
  k_prep_f<<<dim3(16, 16, 8), 256, 0, stream>>>(features, fpack);
  k_gemm<<<dim3(64, 32), 512, 0, stream>>>(fpack, mpack, m_sq, cand);
  k_finalize<<<NPOS, 256, 0, stream>>>(cand, fpack, mb, m_sq, inf_arr, minmax);
  k_maps<<<32, 256, 0, stream>>>(inf_arr, minmax, out, nstd_a);
  k_noise<<<dim3(16, 16, 8), 256, 0, stream>>>(features, noise, nstd_a, out);
}

// Round 3
// 590.307 us; speedup vs baseline: 1.7792x; 1.4398x over previous
//
#include <hip/hip_runtime.h>
#include <stdint.h>
#include <stddef.h>

typedef unsigned short u16;
typedef unsigned int u32;
typedef unsigned long long u64;
typedef __attribute__((ext_vector_type(4))) float f32x4;
typedef __attribute__((ext_vector_type(8))) __bf16 bf16x8;
typedef __attribute__((ext_vector_type(4))) short short4v;

#define NPOS 8192      // B*H*W
#define MROW 16384     // M
#define CDIM 1024      // C

__device__ __forceinline__ u16 f2bf(float x){
  union { float f; u32 u; } z; z.f = x;
  u32 u = z.u;
  return (u16)((u + 0x7fffu + ((u >> 16) & 1u)) >> 16);   // RNE
}
__device__ __forceinline__ float bf2f(u16 h){
  union { u32 u; float f; } z; z.u = ((u32)h) << 16; return z.f;
}
__device__ __forceinline__ u32 fkey(float f){   // order-preserving float->uint
  union { float f; u32 u; } z; z.f = f;
  u32 b = z.u;
  return b ^ ((b & 0x80000000u) ? 0xffffffffu : 0x80000000u);
}
__device__ __forceinline__ float unfkey(u32 u){
  u32 b = (u & 0x80000000u) ? (u ^ 0x80000000u) : ~u;
  union { u32 u; float f; } z; z.u = b; return z.f;
}

__device__ __forceinline__ float block_sum256(float v, float* sb){
  #pragma unroll
  for(int o = 32; o; o >>= 1) v += __shfl_xor(v, o, 64);
  __syncthreads();                    // protect sb across repeated calls
  int lane = threadIdx.x & 63, w = threadIdx.x >> 6;
  if(lane == 0) sb[w] = v;
  __syncthreads();
  return sb[0] + sb[1] + sb[2] + sb[3];   // same fixed order on all threads
}

// async global->LDS, 16B per lane (wave-uniform LDS base + lane*16; global addr is per-lane)
__device__ __forceinline__ void gload16(const u16* g, u16* l){
  __builtin_amdgcn_global_load_lds((const __attribute__((address_space(1))) u32*)g,
                                   (__attribute__((address_space(3))) u32*)l, 16, 0, 0);
}

// ---- K1: memory bank -> bf16-hi pack + row sum of squares (fp32 exact); init minmax ----
__global__ __launch_bounds__(256) void k_prep_mb(const float* __restrict__ mb, u16* __restrict__ mpack,
                                                 float* __restrict__ m_sq, u32* __restrict__ minmax){
  __shared__ float sb[4];
  int row = blockIdx.x, t = threadIdx.x;
  if(row == 0 && t == 0){ minmax[0] = 0x7f800000u; minmax[1] = 0u; }
  const float4 v = ((const float4*)(mb + (size_t)row * CDIM))[t];   // c = 4t..4t+3
  float xs[4] = {v.x, v.y, v.z, v.w};
  short4v hi;
  #pragma unroll
  for(int j = 0; j < 4; j++) hi[j] = (short)f2bf(xs[j]);
  *(short4v*)(mpack + (size_t)row * CDIM + 4 * t) = hi;
  float s = v.x*v.x + v.y*v.y + v.z*v.z + v.w*v.w;
  #pragma unroll
  for(int o = 32; o; o >>= 1) s += __shfl_xor(s, o, 64);
  int lane = t & 63, w = t >> 6;
  if(lane == 0) sb[w] = s;
  __syncthreads();
  if(t == 0) m_sq[row] = sb[0] + sb[1] + sb[2] + sb[3];
}

// ---- K2: features (B,C,HW) -> (N,C) bf16 hi + lo planes via LDS transpose ----
__global__ __launch_bounds__(256) void k_prep_f(const float* __restrict__ feat,
                                                u16* __restrict__ fhi, u16* __restrict__ flo){
  __shared__ float tile[64][65];
  int b = blockIdx.z, c0 = blockIdx.y * 64, hw0 = blockIdx.x * 64;
  int t = threadIdx.x, a = t & 63, g = t >> 6;
  const float* fb = feat + ((size_t)b * CDIM + c0) * 1024 + hw0;
  #pragma unroll 4
  for(int r = 0; r < 16; r++){
    int cL = r * 4 + g;
    tile[cL][a] = fb[(size_t)cL * 1024 + a];      // coalesced over hw
  }
  __syncthreads();
  #pragma unroll 4
  for(int r = 0; r < 16; r++){
    int hwL = r * 4 + g;
    int n = b * 1024 + hw0 + hwL;
    int c = c0 + a;
    float x = tile[a][hwL];
    u16 h = f2bf(x);
    u16 l = f2bf(x - bf2f(h));
    fhi[(size_t)n * CDIM + c] = h;
    flo[(size_t)n * CDIM + c] = l;
  }
}

__device__ __forceinline__ f32x4 mfma16(bf16x8 a, bf16x8 b, f32x4 c){
  return __builtin_amdgcn_mfma_f32_16x16x32_bf16(a, b, c, 0, 0, 0);
}

__device__ __forceinline__ u64 umin64(u64 a, u64 b){ return a < b ? a : b; }
__device__ __forceinline__ u64 umax64(u64 a, u64 b){ return a > b ? a : b; }

// ---- K4: pure-bf16 GEMM, 256x256 tile, 8 waves (2x4), per-wave 128x64, BK=32,
//          4 LDS buffers, depth-3 prefetch, counted vmcnt + raw s_barrier.
//          Epilogue: per-(row, 256-col-tile) TOP-2 argmin keys. ----
__global__ __launch_bounds__(512, 2) void k_gemm(const u16* __restrict__ fhi, const u16* __restrict__ mpack,
                                                 const float* __restrict__ m_sq, u64* __restrict__ cand){
  // [buf][A=0/B=1][row 0..255][32 u16 = 64B = 4 slots of 16B]; LDS slot s holds global block s^((row>>1)&3)
  __shared__ u16 lds[4][2][256][32];   // 128 KB
  int bid = blockIdx.x;
  int ct = (bid & 7) * 8 + ((bid >> 3) & 7);   // XCD-chunked: XCD k owns ct in [8k, 8k+8)
  int rt = bid >> 6;                           // 0..31
  int t = threadIdx.x, lane = t & 63, wid = t >> 6;
  int wm = wid >> 2, wn = wid & 3;        // wave tile: rows wm*128, cols wn*64
  int fr = lane & 15, g = lane >> 4;      // fragment row sel / k-group sel
  const u16* Ag = fhi   + (size_t)(rt * 256) * CDIM;
  const u16* Bg = mpack + (size_t)(ct * 256) * CDIM;
  int sr = t >> 2, sl = t & 3;            // staging: 4 slots per row, 128 rows per instr round

  const f32x4 zero = {0.f, 0.f, 0.f, 0.f};
  f32x4 acc[8][4];
  #pragma unroll
  for(int i = 0; i < 8; i++)
    #pragma unroll
    for(int j = 0; j < 4; j++) acc[i][j] = zero;

  auto STAGE = [&](int buf, int kt){
    #pragma unroll
    for(int j = 0; j < 2; j++){
      int row = sr + j * 128;
      int sb_ = sl ^ ((row >> 1) & 3);                 // inverse swizzle on SOURCE
      gload16(Ag + (size_t)row * CDIM + kt * 32 + sb_ * 8, &lds[buf][0][row][sl * 8]);
    }
    #pragma unroll
    for(int j = 0; j < 2; j++){
      int row = sr + j * 128;
      int sb_ = sl ^ ((row >> 1) & 3);
      gload16(Bg + (size_t)row * CDIM + kt * 32 + sb_ * 8, &lds[buf][1][row][sl * 8]);
    }
  };

  auto COMPUTE = [&](int buf){
    bf16x8 fb[4];
    #pragma unroll
    for(int ni = 0; ni < 4; ni++){
      int r = wn * 64 + ni * 16 + fr;
      fb[ni] = *(const bf16x8*)&lds[buf][1][r][(g ^ ((r >> 1) & 3)) * 8];
    }
    #pragma unroll
    for(int mi = 0; mi < 8; mi++){
      int r = wm * 128 + mi * 16 + fr;
      bf16x8 fa = *(const bf16x8*)&lds[buf][0][r][(g ^ ((r >> 1) & 3)) * 8];
      #pragma unroll
      for(int ni = 0; ni < 4; ni++)
        acc[mi][ni] = mfma16(fa, fb[ni], acc[mi][ni]);
    }
  };

  STAGE(0, 0); STAGE(1, 1); STAGE(2, 2);    // 12 VMEM ops outstanding per thread-wave
  for(int kt = 0; kt < 29; ++kt){
    // stage kt complete (oldest 4 of 12); all waves' reads of buf[(kt-1)&3] done (lgkmcnt+barrier)
    asm volatile("s_waitcnt vmcnt(8) lgkmcnt(0)\n\ts_barrier" ::: "memory");
    STAGE((kt + 3) & 3, kt + 3);            // overwrites buf[(kt-1)&3]
    COMPUTE(kt & 3);
  }
  asm volatile("s_waitcnt vmcnt(8) lgkmcnt(0)\n\ts_barrier" ::: "memory");
  COMPUTE(1);                               // kt=29
  asm volatile("s_waitcnt vmcnt(4) lgkmcnt(0)\n\ts_barrier" ::: "memory");
  COMPUTE(2);                               // kt=30
  asm volatile("s_waitcnt vmcnt(0) lgkmcnt(0)\n\ts_barrier" ::: "memory");
  COMPUTE(3);                               // kt=31

  // ---- epilogue: per-row TOP-2 of (m_sq[col] - 2*cross) over this block's 256 cols ----
  float msq[4];
  #pragma unroll
  for(int ni = 0; ni < 4; ni++) msq[ni] = m_sq[ct * 256 + wn * 64 + ni * 16 + fr];
  __syncthreads();                          // all LDS reads done; safe to reuse as scratch
  u64* rl = (u64*)&lds[0][0][0][0];         // [wn][256 rows][2] = 16KB
  #pragma unroll
  for(int mi = 0; mi < 8; mi++){
    #pragma unroll
    for(int j = 0; j < 4; j++){
      u64 k1 = ~0ull, k2 = ~0ull;
      #pragma unroll
      for(int ni = 0; ni < 4; ni++){
        float v = msq[ni] - 2.f * acc[mi][ni][j];
        u64 key = ((u64)fkey(v) << 32) | (u32)(ct * 256 + wn * 64 + ni * 16 + fr);
        if(key < k1){ k2 = k1; k1 = key; } else if(key < k2){ k2 = key; }
      }
      #pragma unroll
      for(int m = 1; m < 16; m <<= 1){      // butterfly top-2 merge over the 16 fr-lanes
        u64 o1 = __shfl_xor(k1, m, 64), o2 = __shfl_xor(k2, m, 64);
        u64 n1 = umin64(k1, o1);
        u64 n2 = umin64(umax64(k1, o1), umin64(k2, o2));
        k1 = n1; k2 = n2;
      }
      if(fr == 0){
        int rowl = wm * 128 + mi * 16 + g * 4 + j;
        rl[(wn * 256 + rowl) * 2 + 0] = k1;
        rl[(wn * 256 + rowl) * 2 + 1] = k2;
      }
    }
  }
  __syncthreads();
  if(t < 256){
    u64 a1 = rl[t * 2], a2 = rl[t * 2 + 1];
    #pragma unroll
    for(int w = 1; w < 4; w++){
      u64 b1 = rl[(w * 256 + t) * 2], b2 = rl[(w * 256 + t) * 2 + 1];
      u64 n1 = umin64(a1, b1);
      u64 n2 = umin64(umax64(a1, b1), umin64(a2, b2));
      a1 = n1; a2 = n2;
    }
    size_t base = ((size_t)(rt * 256 + t)) * 128 + ct * 2;
    cand[base] = a1; cand[base + 1] = a2;
  }
}

// ---- K5: per row: top-8 of 128 keys, exact fp32 recheck (1 or 8 cands by margin), influence ----
__global__ __launch_bounds__(256) void k_finalize(const u64* __restrict__ cand,
    const u16* __restrict__ fhi, const u16* __restrict__ flo,
    const float* __restrict__ mb, const float* __restrict__ m_sq,
    float* __restrict__ inf_arr, u32* __restrict__ minmax){
  __shared__ float sb[4];
  __shared__ u64 smin[4];
  __shared__ u32 scol[8];
  __shared__ float sval[2];
  int n = blockIdx.x, t = threadIdx.x, lane = t & 63, w = t >> 6;
  u64 key = (t < 128) ? cand[(size_t)n * 128 + t] : ~0ull;

  auto extract_min = [&](int it){
    u64 k = key;
    #pragma unroll
    for(int m = 32; m; m >>= 1){ u64 o = __shfl_xor(k, m, 64); k = o < k ? o : k; }
    if(lane == 0) smin[w] = k;
    __syncthreads();
    u64 m0 = umin64(smin[0], smin[1]);
    u64 m1 = umin64(smin[2], smin[3]);
    u64 m = umin64(m0, m1);
    if(key == m) key = ~0ull;
    if(t == 0){
      scol[it] = (u32)m;
      float v = unfkey((u32)(m >> 32));
      if(it == 0) sval[0] = v;
      if(it == 1) sval[1] = v;
    }
    __syncthreads();
  };
  extract_min(0);
  extract_min(1);
  // margin test: approx-dist2 gap between best and 2nd-best; err sigma ~0.15 -> 4.0 is ~27 sigma
  bool need8 = (sval[1] - sval[0]) <= 4.0f;
  if(need8){ for(int it = 2; it < 8; ++it) extract_min(it); }
  int nr = need8 ? 8 : 1;

  float fv[4];
  {
    short4v hv = *(const short4v*)(fhi + (size_t)n * CDIM + 4 * t);
    short4v lv = *(const short4v*)(flo + (size_t)n * CDIM + 4 * t);
    #pragma unroll
    for(int j = 0; j < 4; j++) fv[j] = bf2f((u16)hv[j]) + bf2f((u16)lv[j]);   // ~f to 2^-17
  }
  float fs = block_sum256(fv[0]*fv[0] + fv[1]*fv[1] + fv[2]*fv[2] + fv[3]*fv[3], sb);

  float bestd = 1e30f; int bestc = 0x7fffffff;
  float4 bmv = {0.f, 0.f, 0.f, 0.f};
  for(int i = 0; i < nr; ++i){             // uniform trip count per block
    int c = (int)scol[i];
    float4 mv = ((const float4*)(mb + (size_t)c * CDIM))[t];
    float p = fv[0]*mv.x + fv[1]*mv.y + fv[2]*mv.z + fv[3]*mv.w;
    float s = block_sum256(p, sb);
    float d = sqrtf(fmaxf(fs + m_sq[c] - 2.f * s, 0.f) + 1e-8f);
    if(d < bestd || (d == bestd && c < bestc)){ bestd = d; bestc = c; bmv = mv; }
  }
  float pa = fabsf(fv[0]-bmv.x) + fabsf(fv[1]-bmv.y) + fabsf(fv[2]-bmv.z) + fabsf(fv[3]-bmv.w);
  float sab = block_sum256(pa, sb);
  if(t == 0){
    float inf = sab / (1024.0f * (bestd + 1e-8f));
    inf_arr[n] = inf;
    atomicMin(&minmax[0], __float_as_uint(inf));   // inf >= 0 -> bit order == float order
    atomicMax(&minmax[1], __float_as_uint(inf));
  }
}

// ---- K6: influence_norm + noise_std maps ----
__global__ void k_maps(const float* __restrict__ inf_arr, const u32* __restrict__ minmax,
                       float* __restrict__ out, float* __restrict__ nstd_arr){
  int n = blockIdx.x * 256 + threadIdx.x;
  float imin = __uint_as_float(minmax[0]);
  float imax = __uint_as_float(minmax[1]);
  float denom = imax - imin;
  float x = inf_arr[n];
  float norm = (denom > 1e-8f) ? ((x - imin) / fmaxf(denom, 1e-8f)) : 0.0f;
  float nsv = 0.01f + norm * 0.49f;
  out[8388608 + n] = norm;       // influence_map
  out[8396800 + n] = nsv;        // noise_std_map
  nstd_arr[n] = nsv;
}

// ---- K7: noised = features + noise * std  (LDS transpose keeps both sides coalesced) ----
__global__ __launch_bounds__(256) void k_noise(const float* __restrict__ feat, const float* __restrict__ noise,
                                               const float* __restrict__ nstd_arr, float* __restrict__ out){
  __shared__ float tile[64][65];
  __shared__ float ns[64];
  int b = blockIdx.z, c0 = blockIdx.y * 64, hw0 = blockIdx.x * 64;
  int t = threadIdx.x, a = t & 63, g = t >> 6;
  if(t < 64) ns[t] = nstd_arr[b * 1024 + hw0 + t];
  #pragma unroll 4
  for(int r = 0; r < 16; r++){
    int j = r * 4 + g;   // hw row
    tile[a][j] = noise[((size_t)(b * 1024 + hw0 + j)) * CDIM + c0 + a];   // coalesced over c
  }
  __syncthreads();
  #pragma unroll 4
  for(int r = 0; r < 16; r++){
    int i = r * 4 + g;   // c offset
    size_t idx = ((size_t)b * CDIM + c0 + i) * 1024 + hw0 + a;
    out[idx] = feat[idx] + tile[i][a] * ns[a];                            // coalesced over hw
  }
}

extern "C" void kernel_launch(void* const* d_in, const int* in_sizes, int n_in,
                              void* d_out, int out_size, void* d_ws, size_t ws_size,
                              hipStream_t stream){
  const float* features = (const float*)d_in[0];
  const float* mb       = (const float*)d_in[1];
  const float* noise    = (const float*)d_in[2];
  float* out = (float*)d_out;
  char* ws = (char*)d_ws;

  // fhi (16MB) + flo (16MB) live in d_out's noised region (33.5MB); overwritten last by k_noise.
  u16* fhi = (u16*)d_out;
  u16* flo = (u16*)d_out + (size_t)NPOS * CDIM;

  size_t off = 0;
  u16* mpack     = (u16*)(ws + off);   off += (size_t)MROW * CDIM * 2;    // 32MB
  float* m_sq    = (float*)(ws + off); off += (size_t)MROW * 4;
  float* inf_arr = (float*)(ws + off); off += (size_t)NPOS * 4;
  float* nstd_a  = (float*)(ws + off); off += (size_t)NPOS * 4;
  u32* minmax    = (u32*)(ws + off);   off += 256;
  u64* cand      = (u64*)(ws + off);   off += (size_t)NPOS * 128 * 8;     // 8MB

  k_prep_mb<<<MROW, 256, 0, stream>>>(mb, mpack, m_sq, minmax);
  k_prep_f<<<dim3(16, 16, 8), 256, 0, stream>>>(features, fhi, flo);
  k_gemm<<<dim3(2048), 512, 0, stream>>>(fhi, mpack, m_sq, cand);
  k_finalize<<<NPOS, 256, 0, stream>>>(cand, fhi, flo, mb, m_sq, inf_arr, minmax);
  k_maps<<<32, 256, 0, stream>>>(inf_arr, minmax, out, nstd_a);
  k_noise<<<dim3(16, 16, 8), 256, 0, stream>>>(features, noise, nstd_a, out);
}

// Round 4
// 584.464 us; speedup vs baseline: 1.7969x; 1.0100x over previous
//
#include <hip/hip_runtime.h>
#include <stdint.h>
#include <stddef.h>

typedef unsigned short u16;
typedef unsigned int u32;
typedef unsigned long long u64;
typedef __attribute__((ext_vector_type(4))) float f32x4;
typedef __attribute__((ext_vector_type(8))) __bf16 bf16x8;
typedef __attribute__((ext_vector_type(4))) short short4v;

#define NPOS 8192      // B*H*W
#define MROW 16384     // M
#define CDIM 1024      // C

__device__ __forceinline__ u16 f2bf(float x){
  union { float f; u32 u; } z; z.f = x;
  u32 u = z.u;
  return (u16)((u + 0x7fffu + ((u >> 16) & 1u)) >> 16);   // RNE
}
__device__ __forceinline__ float bf2f(u16 h){
  union { u32 u; float f; } z; z.u = ((u32)h) << 16; return z.f;
}
__device__ __forceinline__ u32 fkey(float f){   // order-preserving float->uint
  union { float f; u32 u; } z; z.f = f;
  u32 b = z.u;
  return b ^ ((b & 0x80000000u) ? 0xffffffffu : 0x80000000u);
}
__device__ __forceinline__ float unfkey(u32 u){
  u32 b = (u & 0x80000000u) ? (u ^ 0x80000000u) : ~u;
  union { u32 u; float f; } z; z.u = b; return z.f;
}

__device__ __forceinline__ float block_sum256(float v, float* sb){
  #pragma unroll
  for(int o = 32; o; o >>= 1) v += __shfl_xor(v, o, 64);
  __syncthreads();                    // protect sb across repeated calls
  int lane = threadIdx.x & 63, w = threadIdx.x >> 6;
  if(lane == 0) sb[w] = v;
  __syncthreads();
  return sb[0] + sb[1] + sb[2] + sb[3];   // same fixed order on all threads
}

// async global->LDS, 16B per lane (wave-uniform LDS base + lane*16; global addr is per-lane)
__device__ __forceinline__ void gload16(const u16* g, u16* l){
  __builtin_amdgcn_global_load_lds((const __attribute__((address_space(1))) u32*)g,
                                   (__attribute__((address_space(3))) u32*)l, 16, 0, 0);
}

// ---- K1: memory bank -> bf16-hi pack + row sum of squares (fp32 exact); init minmax ----
__global__ __launch_bounds__(256) void k_prep_mb(const float* __restrict__ mb, u16* __restrict__ mpack,
                                                 float* __restrict__ m_sq, u32* __restrict__ minmax){
  __shared__ float sb[4];
  int row = blockIdx.x, t = threadIdx.x;
  if(row == 0 && t == 0){ minmax[0] = 0x7f800000u; minmax[1] = 0u; }
  const float4 v = ((const float4*)(mb + (size_t)row * CDIM))[t];   // c = 4t..4t+3
  float xs[4] = {v.x, v.y, v.z, v.w};
  short4v hi;
  #pragma unroll
  for(int j = 0; j < 4; j++) hi[j] = (short)f2bf(xs[j]);
  *(short4v*)(mpack + (size_t)row * CDIM + 4 * t) = hi;
  float s = v.x*v.x + v.y*v.y + v.z*v.z + v.w*v.w;
  #pragma unroll
  for(int o = 32; o; o >>= 1) s += __shfl_xor(s, o, 64);
  int lane = t & 63, w = t >> 6;
  if(lane == 0) sb[w] = s;
  __syncthreads();
  if(t == 0) m_sq[row] = sb[0] + sb[1] + sb[2] + sb[3];
}

// ---- K2: features (B,C,HW) -> (N,C) bf16 hi + lo planes via LDS transpose ----
__global__ __launch_bounds__(256) void k_prep_f(const float* __restrict__ feat,
                                                u16* __restrict__ fhi, u16* __restrict__ flo){
  __shared__ float tile[64][65];
  int b = blockIdx.z, c0 = blockIdx.y * 64, hw0 = blockIdx.x * 64;
  int t = threadIdx.x, a = t & 63, g = t >> 6;
  const float* fb = feat + ((size_t)b * CDIM + c0) * 1024 + hw0;
  #pragma unroll 4
  for(int r = 0; r < 16; r++){
    int cL = r * 4 + g;
    tile[cL][a] = fb[(size_t)cL * 1024 + a];      // coalesced over hw
  }
  __syncthreads();
  #pragma unroll 4
  for(int r = 0; r < 16; r++){
    int hwL = r * 4 + g;
    int n = b * 1024 + hw0 + hwL;
    int c = c0 + a;
    float x = tile[a][hwL];
    u16 h = f2bf(x);
    u16 l = f2bf(x - bf2f(h));
    fhi[(size_t)n * CDIM + c] = h;
    flo[(size_t)n * CDIM + c] = l;
  }
}

__device__ __forceinline__ f32x4 mfma16(bf16x8 a, bf16x8 b, f32x4 c){
  return __builtin_amdgcn_mfma_f32_16x16x32_bf16(a, b, c, 0, 0, 0);
}

__device__ __forceinline__ u64 umin64(u64 a, u64 b){ return a < b ? a : b; }
__device__ __forceinline__ u64 umax64(u64 a, u64 b){ return a > b ? a : b; }

// ---- K4: pure-bf16 GEMM, 256x256 tile, BK=64, 8 waves (2x4), 8-phase schedule:
//          per K-tile 4 phases (one C-quadrant each, 16 MFMA), each phase consumes one LDS
//          half-tile; counted vmcnt(8) waits (T4), setprio around MFMA (T5), 2 barriers/phase.
//          A-halves: rows [0,128)/[128,256); wave rows = half*128 + wm*64 + [0,64).
//          B-halves: cols [0,128)/[128,256); wave cols = half*128 + wn*32 + [0,32).
//          Epilogue: per-(row, 256-col-tile) TOP-2 argmin keys. ----
__global__ __launch_bounds__(512, 2) void k_gemm(const u16* __restrict__ fhi, const u16* __restrict__ mpack,
                                                 const float* __restrict__ m_sq, u64* __restrict__ cand){
  // [buf][half][row 0..127][64 u16 = 8 slots of 16B]; slot s holds k-block s^(row&7) (XOR swizzle)
  __shared__ u16 lA[2][2][128][64];   // 64 KB
  __shared__ u16 lB[2][2][128][64];   // 64 KB
  int bid = blockIdx.x;
  int ct = (bid & 7) * 8 + ((bid >> 3) & 7);   // XCD-chunked: XCD k owns ct in [8k, 8k+8)
  int rt = bid >> 6;                           // 0..31
  int t = threadIdx.x, lane = t & 63, wid = t >> 6;
  int wm = wid >> 2, wn = wid & 3;
  int fr = lane & 15, g = lane >> 4;
  const u16* Ag = fhi   + (size_t)(rt * 256) * CDIM;
  const u16* Bg = mpack + (size_t)(ct * 256) * CDIM;

  const f32x4 zero = {0.f, 0.f, 0.f, 0.f};
  f32x4 acc[8][4];
  #pragma unroll
  for(int i = 0; i < 8; i++)
    #pragma unroll
    for(int j = 0; j < 4; j++) acc[i][j] = zero;

  bf16x8 AR[4][2];                 // current qm-half A frags
  bf16x8 B0R[2][2], B1R[2][2];     // B frags for ni01 (half0) / ni23 (half1)

  // stage one 16KB half-tile (128 rows x 64 k): 2 gloads/thread, linear LDS dest,
  // inverse-swizzled global source (rule #21)
#define STAGEA(BUF, H, KT) do{ \
    _Pragma("unroll") for(int j_ = 0; j_ < 2; j_++){ \
      int idx_ = j_ * 512 + t; int rl_ = idx_ >> 3, sl_ = idx_ & 7; \
      gload16(Ag + (size_t)((H) * 128 + rl_) * CDIM + (KT) * 64 + ((sl_ ^ (rl_ & 7)) << 3), \
              &lA[BUF][H][rl_][sl_ << 3]); } }while(0)
#define STAGEB(BUF, H, KT) do{ \
    _Pragma("unroll") for(int j_ = 0; j_ < 2; j_++){ \
      int idx_ = j_ * 512 + t; int rl_ = idx_ >> 3, sl_ = idx_ & 7; \
      gload16(Bg + (size_t)((H) * 128 + rl_) * CDIM + (KT) * 64 + ((sl_ ^ (rl_ & 7)) << 3), \
              &lB[BUF][H][rl_][sl_ << 3]); } }while(0)

#define DSA(BUF, QM) do{ \
    _Pragma("unroll") for(int i_ = 0; i_ < 4; i_++){ \
      int rl_ = wm * 64 + i_ * 16 + fr; \
      _Pragma("unroll") for(int kc_ = 0; kc_ < 2; kc_++) \
        AR[i_][kc_] = *(const bf16x8*)&lA[BUF][QM][rl_][(((kc_ << 2) | g) ^ (rl_ & 7)) << 3]; \
    } }while(0)
#define DSB(BUF, QN, DST) do{ \
    _Pragma("unroll") for(int i_ = 0; i_ < 2; i_++){ \
      int rl_ = wn * 32 + i_ * 16 + fr; \
      _Pragma("unroll") for(int kc_ = 0; kc_ < 2; kc_++) \
        DST[i_][kc_] = *(const bf16x8*)&lB[BUF][QN][rl_][(((kc_ << 2) | g) ^ (rl_ & 7)) << 3]; \
    } }while(0)

#define MFMAQ(QM, QN, BR) do{ \
    _Pragma("unroll") for(int kc_ = 0; kc_ < 2; kc_++) \
      _Pragma("unroll") for(int i_ = 0; i_ < 4; i_++) \
        _Pragma("unroll") for(int jn_ = 0; jn_ < 2; jn_++) \
          acc[(QM)*4 + i_][(QN)*2 + jn_] = mfma16(AR[i_][kc_], BR[jn_][kc_], acc[(QM)*4 + i_][(QN)*2 + jn_]); \
    }while(0)

#define SYNCV(N) asm volatile("s_waitcnt vmcnt(" #N ")\n\ts_barrier" ::: "memory")
#define SYNCB()  asm volatile("s_barrier" ::: "memory")
#define LG0()    do{ asm volatile("s_waitcnt lgkmcnt(0)" ::: "memory"); __builtin_amdgcn_sched_barrier(0); }while(0)
#define PRIO1()  __builtin_amdgcn_s_setprio(1)
#define PRIO0()  __builtin_amdgcn_s_setprio(0)

  // one K-tile = 4 phases; stages: ph1->B1(t+1), ph2->A1(t+1), ph3->A0(t+2), ph4->B0(t+2)
#define TILE(BUF, KT, S1, S2, S3, S4, SY1, SY2, SY4) \
  /*ph1 q(0,0)*/ DSA(BUF, 0); DSB(BUF, 0, B0R); S1; SY1; LG0(); \
  PRIO1(); MFMAQ(0, 0, B0R); PRIO0(); SYNCB(); \
  /*ph2 q(0,1)*/ DSB(BUF, 1, B1R); S2; SY2; LG0(); \
  PRIO1(); MFMAQ(0, 1, B1R); PRIO0(); SYNCB(); \
  /*ph3 q(1,0)*/ DSA(BUF, 1); S3; SYNCB(); LG0(); \
  PRIO1(); MFMAQ(1, 0, B0R); PRIO0(); SYNCB(); \
  /*ph4 q(1,1)*/ S4; SY4; \
  PRIO1(); MFMAQ(1, 1, B1R); PRIO0(); SYNCB();

  // prologue: issue halves in consumption order with lag: A0(0),B0(0),B1(0),A1(0),A0(1),B0(1)
  STAGEA(0, 0, 0); STAGEB(0, 0, 0); STAGEB(0, 1, 0); STAGEA(0, 1, 0);
  STAGEA(1, 0, 1); STAGEB(1, 0, 1);
  SYNCV(8);   // A0(0),B0(0) complete

  for(int tt = 0; tt < 14; tt += 2){
    TILE(0, tt,     STAGEB(1, 1, tt + 1), STAGEA(1, 1, tt + 1),
                    STAGEA(0, 0, tt + 2), STAGEB(0, 0, tt + 2), SYNCV(8), SYNCV(8), SYNCV(8))
    TILE(1, tt + 1, STAGEB(0, 1, tt + 2), STAGEA(0, 1, tt + 2),
                    STAGEA(1, 0, tt + 3), STAGEB(1, 0, tt + 3), SYNCV(8), SYNCV(8), SYNCV(8))
  }
  // t=14: stage only tile-15 halves B1,A1; drain to vmcnt(4) for A0(15),B0(15)
  TILE(0, 14, STAGEB(1, 1, 15), STAGEA(1, 1, 15), (void)0, (void)0, SYNCV(8), SYNCV(8), SYNCV(4))
  // t=15: no stages; tail waits 2 -> 0
  TILE(1, 15, (void)0, (void)0, (void)0, (void)0, SYNCV(2), SYNCV(0), SYNCB())

  // ---- epilogue: per-row TOP-2 of (m_sq[col] - 2*cross) over this block's 256 cols ----
  // C(ni,fr) = (ni>>1)*128 + wn*32 + (ni&1)*16 + fr ; R(mi,g,j) = (mi>>2)*128 + wm*64 + (mi&3)*16 + g*4 + j
  float msq[4];
  #pragma unroll
  for(int ni = 0; ni < 4; ni++)
    msq[ni] = m_sq[ct * 256 + (ni >> 1) * 128 + wn * 32 + (ni & 1) * 16 + fr];
  __syncthreads();
  u64* rl = (u64*)&lA[0][0][0][0];          // 1024 u64 = 8KB scratch
  #pragma unroll
  for(int mi = 0; mi < 8; mi++){
    #pragma unroll
    for(int j = 0; j < 4; j++){
      u64 k1 = ~0ull, k2 = ~0ull;
      #pragma unroll
      for(int ni = 0; ni < 4; ni++){
        float v = msq[ni] - 2.f * acc[mi][ni][j];
        u64 key = ((u64)fkey(v) << 32) | (u32)(ct * 256 + (ni >> 1) * 128 + wn * 32 + (ni & 1) * 16 + fr);
        if(key < k1){ k2 = k1; k1 = key; } else if(key < k2){ k2 = key; }
      }
      #pragma unroll
      for(int m = 1; m < 16; m <<= 1){      // butterfly top-2 merge over the 16 fr-lanes
        u64 o1 = __shfl_xor(k1, m, 64), o2 = __shfl_xor(k2, m, 64);
        u64 n1 = umin64(k1, o1);
        u64 n2 = umin64(umax64(k1, o1), umin64(k2, o2));
        k1 = n1; k2 = n2;
      }
      if(fr == 0){
        int rowl = (mi >> 2) * 128 + wm * 64 + (mi & 3) * 16 + g * 4 + j;
        rl[(wn * 256 + rowl) * 2 + 0] = k1;
        rl[(wn * 256 + rowl) * 2 + 1] = k2;
      }
    }
  }
  __syncthreads();
  if(t < 256){
    u64 a1 = rl[t * 2], a2 = rl[t * 2 + 1];
    #pragma unroll
    for(int w = 1; w < 4; w++){
      u64 b1 = rl[(w * 256 + t) * 2], b2 = rl[(w * 256 + t) * 2 + 1];
      u64 n1 = umin64(a1, b1);
      u64 n2 = umin64(umax64(a1, b1), umin64(a2, b2));
      a1 = n1; a2 = n2;
    }
    size_t base = ((size_t)(rt * 256 + t)) * 128 + ct * 2;
    cand[base] = a1; cand[base + 1] = a2;
  }
#undef STAGEA
#undef STAGEB
#undef DSA
#undef DSB
#undef MFMAQ
#undef SYNCV
#undef SYNCB
#undef LG0
#undef PRIO1
#undef PRIO0
#undef TILE
}

// ---- K5: per row: top-8 of 128 keys, exact fp32 recheck (1 or 8 cands by margin), influence ----
__global__ __launch_bounds__(256) void k_finalize(const u64* __restrict__ cand,
    const u16* __restrict__ fhi, const u16* __restrict__ flo,
    const float* __restrict__ mb, const float* __restrict__ m_sq,
    float* __restrict__ inf_arr, u32* __restrict__ minmax){
  __shared__ float sb[4];
  __shared__ u64 smin[4];
  __shared__ u32 scol[8];
  __shared__ float sval[2];
  int n = blockIdx.x, t = threadIdx.x, lane = t & 63, w = t >> 6;
  u64 key = (t < 128) ? cand[(size_t)n * 128 + t] : ~0ull;

  auto extract_min = [&](int it){
    u64 k = key;
    #pragma unroll
    for(int m = 32; m; m >>= 1){ u64 o = __shfl_xor(k, m, 64); k = o < k ? o : k; }
    if(lane == 0) smin[w] = k;
    __syncthreads();
    u64 m0 = umin64(smin[0], smin[1]);
    u64 m1 = umin64(smin[2], smin[3]);
    u64 m = umin64(m0, m1);
    if(key == m) key = ~0ull;
    if(t == 0){
      scol[it] = (u32)m;
      float v = unfkey((u32)(m >> 32));
      if(it == 0) sval[0] = v;
      if(it == 1) sval[1] = v;
    }
    __syncthreads();
  };
  extract_min(0);
  extract_min(1);
  // margin test: approx-dist2 gap between best and 2nd-best; err sigma ~0.15 -> 4.0 is ~27 sigma
  bool need8 = (sval[1] - sval[0]) <= 4.0f;
  if(need8){ for(int it = 2; it < 8; ++it) extract_min(it); }
  int nr = need8 ? 8 : 1;

  float fv[4];
  {
    short4v hv = *(const short4v*)(fhi + (size_t)n * CDIM + 4 * t);
    short4v lv = *(const short4v*)(flo + (size_t)n * CDIM + 4 * t);
    #pragma unroll
    for(int j = 0; j < 4; j++) fv[j] = bf2f((u16)hv[j]) + bf2f((u16)lv[j]);   // ~f to 2^-17
  }
  float fs = block_sum256(fv[0]*fv[0] + fv[1]*fv[1] + fv[2]*fv[2] + fv[3]*fv[3], sb);

  float bestd = 1e30f; int bestc = 0x7fffffff;
  float4 bmv = {0.f, 0.f, 0.f, 0.f};
  for(int i = 0; i < nr; ++i){             // uniform trip count per block
    int c = (int)scol[i];
    float4 mv = ((const float4*)(mb + (size_t)c * CDIM))[t];
    float p = fv[0]*mv.x + fv[1]*mv.y + fv[2]*mv.z + fv[3]*mv.w;
    float s = block_sum256(p, sb);
    float d = sqrtf(fmaxf(fs + m_sq[c] - 2.f * s, 0.f) + 1e-8f);
    if(d < bestd || (d == bestd && c < bestc)){ bestd = d; bestc = c; bmv = mv; }
  }
  float pa = fabsf(fv[0]-bmv.x) + fabsf(fv[1]-bmv.y) + fabsf(fv[2]-bmv.z) + fabsf(fv[3]-bmv.w);
  float sab = block_sum256(pa, sb);
  if(t == 0){
    float inf = sab / (1024.0f * (bestd + 1e-8f));
    inf_arr[n] = inf;
    atomicMin(&minmax[0], __float_as_uint(inf));   // inf >= 0 -> bit order == float order
    atomicMax(&minmax[1], __float_as_uint(inf));
  }
}

// ---- K6: influence_norm + noise_std maps ----
__global__ void k_maps(const float* __restrict__ inf_arr, const u32* __restrict__ minmax,
                       float* __restrict__ out, float* __restrict__ nstd_arr){
  int n = blockIdx.x * 256 + threadIdx.x;
  float imin = __uint_as_float(minmax[0]);
  float imax = __uint_as_float(minmax[1]);
  float denom = imax - imin;
  float x = inf_arr[n];
  float norm = (denom > 1e-8f) ? ((x - imin) / fmaxf(denom, 1e-8f)) : 0.0f;
  float nsv = 0.01f + norm * 0.49f;
  out[8388608 + n] = norm;       // influence_map
  out[8396800 + n] = nsv;        // noise_std_map
  nstd_arr[n] = nsv;
}

// ---- K7: noised = features + noise * std  (LDS transpose keeps both sides coalesced) ----
__global__ __launch_bounds__(256) void k_noise(const float* __restrict__ feat, const float* __restrict__ noise,
                                               const float* __restrict__ nstd_arr, float* __restrict__ out){
  __shared__ float tile[64][65];
  __shared__ float ns[64];
  int b = blockIdx.z, c0 = blockIdx.y * 64, hw0 = blockIdx.x * 64;
  int t = threadIdx.x, a = t & 63, g = t >> 6;
  if(t < 64) ns[t] = nstd_arr[b * 1024 + hw0 + t];
  #pragma unroll 4
  for(int r = 0; r < 16; r++){
    int j = r * 4 + g;   // hw row
    tile[a][j] = noise[((size_t)(b * 1024 + hw0 + j)) * CDIM + c0 + a];   // coalesced over c
  }
  __syncthreads();
  #pragma unroll 4
  for(int r = 0; r < 16; r++){
    int i = r * 4 + g;   // c offset
    size_t idx = ((size_t)b * CDIM + c0 + i) * 1024 + hw0 + a;
    out[idx] = feat[idx] + tile[i][a] * ns[a];                            // coalesced over hw
  }
}

extern "C" void kernel_launch(void* const* d_in, const int* in_sizes, int n_in,
                              void* d_out, int out_size, void* d_ws, size_t ws_size,
                              hipStream_t stream){
  const float* features = (const float*)d_in[0];
  const float* mb       = (const float*)d_in[1];
  const float* noise    = (const float*)d_in[2];
  float* out = (float*)d_out;
  char* ws = (char*)d_ws;

  // fhi (16MB) + flo (16MB) live in d_out's noised region (33.5MB); overwritten last by k_noise.
  u16* fhi = (u16*)d_out;
  u16* flo = (u16*)d_out + (size_t)NPOS * CDIM;

  size_t off = 0;
  u16* mpack     = (u16*)(ws + off);   off += (size_t)MROW * CDIM * 2;    // 32MB
  float* m_sq    = (float*)(ws + off); off += (size_t)MROW * 4;
  float* inf_arr = (float*)(ws + off); off += (size_t)NPOS * 4;
  float* nstd_a  = (float*)(ws + off); off += (size_t)NPOS * 4;
  u32* minmax    = (u32*)(ws + off);   off += 256;
  u64* cand      = (u64*)(ws + off);   off += (size_t)NPOS * 128 * 8;     // 8MB

  k_prep_mb<<<MROW, 256, 0, stream>>>(mb, mpack, m_sq, minmax);
  k_prep_f<<<dim3(16, 16, 8), 256, 0, stream>>>(features, fhi, flo);
  k_gemm<<<dim3(2048), 512, 0, stream>>>(fhi, mpack, m_sq, cand);
  k_finalize<<<NPOS, 256, 0, stream>>>(cand, fhi, flo, mb, m_sq, inf_arr, minmax);
  k_maps<<<32, 256, 0, stream>>>(inf_arr, minmax, out, nstd_a);
  k_noise<<<dim3(16, 16, 8), 256, 0, stream>>>(features, noise, nstd_a, out);
}